// Round 10
// baseline (96.040 us; speedup 1.0000x reference)
//
#include <hip/hip_runtime.h>

#define HH 512
#define WW 1024
#define HWSZ (HH*WW)
#define NCLS 19
#define KEEP 128
#define CTHR 0.1f
#define NBLK 512            // nms tiles = (WW/64)*(HH/16)
typedef unsigned long long u64;

// monotone value->bin map, fine resolution where the data lives (v in [0.5,1))
static __device__ __forceinline__ int key_bin(u64 k) {
    unsigned u = (unsigned)(k >> 32);
    if (u >= 0x3F000000u) {
        int b = 4096 + (int)((u - 0x3F000000u) >> 11);
        return b > 8191 ? 8191 : b;
    }
    return (int)(u >> 19);   // < 2016
}

// wave-aggregated LDS push; call sites must be wave-uniform
static __device__ __forceinline__ int lds_push(int* cnt, bool want, int lane, u64 lmask_lt) {
    u64 mask = __ballot(want);
    int pos = -1;
    if (mask) {
        int leader = __builtin_ctzll(mask);
        int bpos = 0;
        if (lane == leader) bpos = atomicAdd(cnt, (int)__popcll(mask));
        bpos = __shfl(bpos, leader);
        if (want) pos = bpos + (int)__popcll(mask & lmask_lt);
    }
    return pos;
}

static __device__ __forceinline__ void bitonic_lds(u64* b, int m, int tid) {
    for (int kk = 2; kk <= m; kk <<= 1) {
        for (int j = kk >> 1; j; j >>= 1) {
            for (int i = tid; i < m; i += 256) {
                int ixj = i ^ j;
                if (ixj > i) {
                    bool desc = ((i & kk) == 0);
                    u64 a = b[i], c = b[ixj];
                    if ((a < c) == desc) { b[i] = c; b[ixj] = a; }
                }
            }
            __syncthreads();
        }
    }
}

// 256-elem descending bitonic, 1 elem/thread: shfl for j<64, LDS for j>=64
static __device__ __forceinline__ void bitonic256_reg(u64* ov, int tid) {
    u64 a = ov[tid];
    __syncthreads();
    for (int kk = 2; kk <= 256; kk <<= 1) {
        bool desc = ((tid & kk) == 0);
        for (int j = kk >> 1; j; j >>= 1) {
            u64 b;
            if (j >= 64) {
                ov[tid] = a; __syncthreads();
                b = ov[tid ^ j]; __syncthreads();
            } else {
                b = __shfl_xor(a, j);
            }
            bool up = ((tid & j) == 0);
            bool keepMax = (up == desc);
            a = keepMax ? (a > b ? a : b) : (a < b ? a : b);
        }
    }
    ov[tid] = a;
    __syncthreads();
}

// ---------------- NMS (7x7, SAME) -> transposed survivor segments; also inits sync cells ----
__global__ void nms_kernel(const float* __restrict__ hm_in, float* __restrict__ hm_out,
                           u64* __restrict__ keys, int* __restrict__ blkcnt, int maxpb,
                           int* __restrict__ claimp, int* __restrict__ flagp)
{
    const int TX = 64, TY = 16;
    __shared__ float sin_[TY + 6][TX + 6];
    __shared__ float shm[TY + 6][TX];
    __shared__ u64 lkeys[TX * TY];
    __shared__ int lcnt;

    if (blockIdx.x == 0 && threadIdx.x == 0) { *claimp = 0; *flagp = 0; }  // visible at kernel end
    if (threadIdx.x == 0) lcnt = 0;
    int bx = blockIdx.x & 15, by = blockIdx.x >> 4;
    int ox = bx * TX, oy = by * TY;

    for (int i = threadIdx.x; i < (TY + 6) * (TX + 6); i += blockDim.x) {
        int ly = i / (TX + 6), lx = i % (TX + 6);
        int gy = oy + ly - 3, gx = ox + lx - 3;
        float v = 0.f;
        if (gy >= 0 && gy < HH && gx >= 0 && gx < WW) {
            float t = hm_in[gy * WW + gx];
            v = (t > CTHR) ? t : 0.f;
        }
        sin_[ly][lx] = v;
    }
    __syncthreads();
    for (int i = threadIdx.x; i < (TY + 6) * TX; i += blockDim.x) {
        int ly = i / TX, lx = i % TX;
        float m = sin_[ly][lx];
#pragma unroll
        for (int d = 1; d < 7; d++) m = fmaxf(m, sin_[ly][lx + d]);
        shm[ly][lx] = m;
    }
    __syncthreads();
    for (int i = threadIdx.x; i < TY * TX; i += blockDim.x) {
        int ly = i / TX, lx = i % TX;
        float m = shm[ly][lx];
#pragma unroll
        for (int d = 1; d < 7; d++) m = fmaxf(m, shm[ly + d][lx]);
        float c = sin_[ly + 3][lx + 3];
        float o = (m == c) ? c : 0.f;
        int gy = oy + ly, gx = ox + lx;
        hm_out[gy * WW + gx] = o;
        if (o > 0.f) {
            int pos = atomicAdd(&lcnt, 1);
            lkeys[pos] = ((u64)__float_as_uint(o) << 32) |
                         (u64)(0xFFFFFFFFu - (unsigned)(gy * WW + gx));
        }
    }
    __syncthreads();
    int n = lcnt < maxpb ? lcnt : maxpb;
    if (threadIdx.x == 0) blkcnt[blockIdx.x] = n;
    for (int i = threadIdx.x; i < n; i += blockDim.x)
        keys[(size_t)i * NBLK + blockIdx.x] = lkeys[i];
}

// ---------------- fused: [winner: full top-128 select] + assign for all 2048 tiles ----------
// smem union (35904 B):
//  select: scnt[512] @0 (2048) | hist[8192] @2048 (32768; ov[2048] u64 overlays after cutoff)
//          | cs[256] @34816 (1024)
//  assign: slog[4864] @0 (19456) | sc[128] @19456 (2048) | skept[128] @21504 (2048)
//          | skidx[128] @23552 (512)
__global__ void __launch_bounds__(256) fused_kernel(
        const float* __restrict__ logits, const float* __restrict__ offs,
        const int* __restrict__ thing_ids, int n_thing,
        const u64* __restrict__ keys, const int* __restrict__ blkcnt, int maxpb,
        float4* __restrict__ centers, int* __restrict__ claimp, int* __restrict__ flagp,
        float* __restrict__ out)
{
    __shared__ __align__(16) char smem[35904];
    __shared__ int s_win, s_n, s_m, s_bin, s_chunk, s_K, s_nkept;
    __shared__ unsigned s_cabove;
    __shared__ float sred[16];
    __shared__ float ured[4];
    __shared__ int wcnt[4];
    __shared__ int sids[32];

    int tid = threadIdx.x, lane = tid & 63, wid = tid >> 6;
    u64 lmask_lt = (1ull << lane) - 1ull;

    if (tid == 0) s_win = (blockIdx.x < 64) ? (atomicCAS(claimp, 0, 1) == 0) : 0;
    if (tid < n_thing) sids[tid] = thing_ids[tid];
    __syncthreads();

    // ================= winner: full select over 512 segments =================
    if (s_win) {
        int* scnt = (int*)smem;
        unsigned* hist = (unsigned*)(smem + 2048);
        u64* ov = (u64*)(smem + 2048);
        unsigned* cs = (unsigned*)(smem + 34816);
        if (tid == 0) { s_n = 0; s_m = 0; s_bin = 8192; s_chunk = -1; }
        int c0 = blkcnt[2 * tid];  c0 = c0 < 0 ? 0 : (c0 > maxpb ? maxpb : c0);
        int c1 = blkcnt[2 * tid + 1]; c1 = c1 < 0 ? 0 : (c1 > maxpb ? maxpb : c1);
        scnt[2 * tid] = c0; scnt[2 * tid + 1] = c1;
        int mx = c0 > c1 ? c0 : c1;
        for (int d = 32; d; d >>= 1) { int o = __shfl_xor(mx, d); mx = mx > o ? mx : o; }
        if (lane == 0) wcnt[wid] = mx;
        { uint4* h4 = (uint4*)hist; for (int i = tid; i < 2048; i += 256) h4[i] = make_uint4(0,0,0,0); }
        __syncthreads();
        int m01 = wcnt[0] > wcnt[1] ? wcnt[0] : wcnt[1];
        int m23 = wcnt[2] > wcnt[3] ? wcnt[2] : wcnt[3];
        int maxc = m01 > m23 ? m01 : m23;
        int iters = (maxc * NBLK + 1023) >> 10;

        // hist pass (coalesced transposed reads, 4 independent loads per iter)
        for (int it = 0; it < iters; ++it) {
            u64 kv[4]; bool pv[4];
#pragma unroll
            for (int u = 0; u < 4; u++) {
                int i = it * 1024 + u * 256 + tid;
                int sg = i & (NBLK - 1), sl = i >> 9;
                pv[u] = (sl < scnt[sg]);               // sl >= maxc -> false
                kv[u] = pv[u] ? keys[(size_t)sl * NBLK + sg] : 0ull;
            }
#pragma unroll
            for (int u = 0; u < 4; u++)
                if (pv[u]) atomicAdd(&hist[key_bin(kv[u])], 1u);
        }
        __syncthreads();

        // cutoff: suffix sums of 256 chunk sums; cs[0] = total survivors
        unsigned c = 0;
        for (int i = 0; i < 32; i++) c += hist[tid * 32 + i];
        cs[tid] = c;
        __syncthreads();
        for (int d = 1; d < 256; d <<= 1) {
            unsigned v = cs[tid];
            unsigned w = (tid + d < 256) ? cs[tid + d] : 0u;
            __syncthreads();
            cs[tid] = v + w;
            __syncthreads();
        }
        if (tid == 0) s_K = (int)cs[0] < KEEP ? (int)cs[0] : KEEP;
        __syncthreads();
        int K = s_K;
        unsigned above = (tid < 255) ? cs[tid + 1] : 0u;
        if (K > 0 && above < (unsigned)K && (unsigned)K <= cs[tid]) { s_chunk = tid; s_cabove = above; }
        __syncthreads();
        if (tid < 64 && s_chunk >= 0) {
            int ch = s_chunk;
            unsigned v = (tid < 32) ? hist[ch * 32 + tid] : 0u;
            unsigned s = v;
            for (int d = 1; d < 64; d <<= 1) {
                unsigned o = __shfl_down(s, d);
                if (tid + d < 64) s += o;
            }
            unsigned ab = s_cabove + (s - v);
            if (tid < 32 && ab < (unsigned)K && (unsigned)K <= s_cabove + s)
                s_bin = ch * 32 + tid;
        }
        __syncthreads();
        int cb = s_bin;

        // collect pass (hist dead -> ov overlay); wave-uniform trips for lds_push
        for (int it = 0; it < iters; ++it) {
#pragma unroll
            for (int u = 0; u < 4; u++) {
                int i = it * 1024 + u * 256 + tid;
                int sg = i & (NBLK - 1), sl = i >> 9;
                bool pv = (sl < scnt[sg]);
                u64 kv = pv ? keys[(size_t)sl * NBLK + sg] : 0ull;
                bool want = pv && key_bin(kv) >= cb;
                int pos = lds_push(&s_m, want, lane, lmask_lt);
                if (want && pos < 2048) ov[pos] = kv;
            }
        }
        __syncthreads();
        int n = s_m; if (n > 2048) n = 2048;
        int m = 256; while (m < n) m <<= 1;
        for (int i = tid; i < m; i += 256) if (i >= n) ov[i] = 0ull;
        __syncthreads();
        if (m == 256) bitonic256_reg(ov, tid); else bitonic_lds(ov, m, tid);

        if (tid < KEEP) {
            u64 k64 = ov[tid];
            float sc_, cy, cx, a;
            if (k64 == 0ull) { sc_ = 0.f; cy = 0.f; cx = 0.f; a = 0.f; }
            else {
                sc_ = __uint_as_float((unsigned)(k64 >> 32));
                unsigned idx = 0xFFFFFFFFu - (unsigned)(k64 & 0xFFFFFFFFu);
                cy = (float)(idx / WW);
                cx = (float)(idx % WW);
                a = cy * cy + cx * cx;                 // exact (< 2^24)
            }
            centers[tid] = make_float4(cy, cx, a, sc_);
        }
        __threadfence();
        __syncthreads();
        if (tid == 0) atomicExch(flagp, 1);            // release: centers visible device-wide
    }

    // ================= assign (all blocks; winner continues after select) =================
    float*  slog  = (float*)smem;
    float4* sc    = (float4*)(smem + 19456);
    float4* skept = (float4*)(smem + 21504);
    int*    skidx = (int*)(smem + 23552);

    int tile = blockIdx.x;
    int bx = tile & 63, by = tile >> 6;
    int lr = tid >> 4, lc = tid & 15;
    int gy = by * 16 + lr, gx = bx * 16 + lc;
    int p  = gy * WW + gx;

    __syncthreads();   // winner: select LDS dead; all blocks: uniform barrier count from here
    {
        const float4* src4 = (const float4*)(logits + ((size_t)(by * 16) * WW + bx * 16) * NCLS);
        float4* dst4 = (float4*)slog;
        for (int i = tid; i < 16 * 76; i += 256) {
            int r = i / 76, cidx = i % 76;
            dst4[i] = src4[(size_t)r * 4864 + cidx];
        }
    }

    float2 off2 = ((const float2*)offs)[p];
    float py = __fadd_rn((float)gy, off2.x);
    float px = __fadd_rn((float)gx, off2.y);

    float ymn = py, ymx = py, xmn = px, xmx = px;
    for (int d = 32; d; d >>= 1) {
        ymn = fminf(ymn, __shfl_xor(ymn, d));
        ymx = fmaxf(ymx, __shfl_xor(ymx, d));
        xmn = fminf(xmn, __shfl_xor(xmn, d));
        xmx = fmaxf(xmx, __shfl_xor(xmx, d));
    }
    if (lane == 0) {
        sred[wid * 4 + 0] = ymn; sred[wid * 4 + 1] = ymx;
        sred[wid * 4 + 2] = xmn; sred[wid * 4 + 3] = xmx;
    }

    // gate: centers ready? (select usually already hidden under the staging above)
    if (tid == 0) {
        while (__hip_atomic_load(flagp, __ATOMIC_RELAXED, __HIP_MEMORY_SCOPE_AGENT) == 0)
            __builtin_amdgcn_s_sleep(8);
        __threadfence();                               // acquire: invalidate stale lines
    }
    __syncthreads();                                   // slog, sred ready; flag observed
    if (tid < KEEP) sc[tid] = centers[tid];
    __syncthreads();

    ymn = fminf(fminf(sred[0], sred[4]), fminf(sred[8],  sred[12]));
    ymx = fmaxf(fmaxf(sred[1], sred[5]), fmaxf(sred[9],  sred[13]));
    xmn = fminf(fminf(sred[2], sred[6]), fminf(sred[10], sred[14]));
    xmx = fmaxf(fmaxf(sred[3], sred[7]), fmaxf(sred[11], sred[15]));

    float L = INFINITY, U = INFINITY;
    bool valid = false;
    if (tid < KEEP) {
        float4 c4 = sc[tid];
        valid = (c4.w > 0.f);
        if (valid) {
            float dyl = fmaxf(fmaxf(ymn - c4.x, c4.x - ymx), 0.f);
            float dxl = fmaxf(fmaxf(xmn - c4.y, c4.y - xmx), 0.f);
            L = dyl * dyl + dxl * dxl;
            float dyu = fmaxf(fabsf(c4.x - ymn), fabsf(c4.x - ymx));
            float dxu = fmaxf(fabsf(c4.y - xmn), fabsf(c4.y - xmx));
            U = dyu * dyu + dxu * dxu;
        }
    }
    float u = U;
    for (int d = 32; d; d >>= 1) u = fminf(u, __shfl_xor(u, d));
    if (lane == 0) ured[wid] = u;
    __syncthreads();
    float Umin = fminf(fminf(ured[0], ured[1]), fminf(ured[2], ured[3]));

    bool keep = valid && (L <= Umin + 8.0f);           // margin 8 >> rounding slop ~2
    u64 kmask = __ballot(keep);
    int prefix = __popcll(kmask & lmask_lt);
    if (lane == 0) wcnt[wid] = __popcll(kmask);
    __syncthreads();
    int base = (wid == 1) ? wcnt[0] : 0;
    if (keep) { skept[base + prefix] = sc[tid]; skidx[base + prefix] = tid; }
    if (tid == 0) s_nkept = wcnt[0] + wcnt[1];
    __syncthreads();

    const float* l = slog + tid * NCLS;                // odd stride -> 2-way LDS alias, free
    float best = l[0];
    int cls = 0;
#pragma unroll
    for (int cc = 1; cc < NCLS; cc++) {
        float v = l[cc];
        if (v > best) { best = v; cls = cc; }
    }
    bool thing = false;
    for (int j = 0; j < n_thing; j++) thing = thing || (cls == sids[j]);

    float b = __fadd_rn(__fmul_rn(py, py), __fmul_rn(px, px));

    float bestd = INFINITY;
    int bi = -1;
    int nk = s_nkept;
    for (int k = 0; k < nk; k++) {
        float4 c4 = skept[k];
        // replicate f32 gemm: m = fma(cx,px, rn(cy*py)); d2 = rn(rn(a-2m)+b)
        float m  = __fmaf_rn(c4.y, px, __fmul_rn(c4.x, py));
        float d2 = __fadd_rn(__fsub_rn(c4.z, __fadd_rn(m, m)), b);
        if (d2 < bestd) { bestd = d2; bi = k; }
    }

    float inst, smap;
    if (bi < 0) { inst = thing ? 1.f : 0.f; smap = 0.f; }
    else {
        inst = thing ? (float)(skidx[bi] + 1) : 0.f;
        smap = thing ? skept[bi].w : 0.f;
    }
    out[p] = inst;
    out[2 * HWSZ + p] = smap;
    out[3 * HWSZ + p] = (float)cls;
}

extern "C" void kernel_launch(void* const* d_in, const int* in_sizes, int n_in,
                              void* d_out, int out_size, void* d_ws, size_t ws_size,
                              hipStream_t stream) {
    const float* logits = (const float*)d_in[0];
    const float* heat   = (const float*)d_in[1];
    const float* offs   = (const float*)d_in[2];
    const int*   tids   = (const int*)d_in[3];
    int n_thing = in_sizes[3];
    if (n_thing > 32) n_thing = 32;

    float* out = (float*)d_out;
    char* ws = (char*)d_ws;
    // layout: blkcnt[512] @0 | claim @2048 | flag @2112 | centers @4096 | keys @32768
    int* blkcnt = (int*)ws;
    int* claimp = (int*)(ws + 2048);
    int* flagp  = (int*)(ws + 2112);
    float4* centers = (float4*)(ws + 4096);
    long long avail = (long long)ws_size - 32768;
    int maxpb = (int)(avail / (NBLK * 8));
    if (maxpb > 120) maxpb = 120;
    if (maxpb < 16) maxpb = 16;
    u64* keys = (u64*)(ws + 32768);   // transposed [maxpb][512]

    nms_kernel<<<dim3(NBLK), dim3(256), 0, stream>>>(heat, out + HWSZ, keys, blkcnt, maxpb,
                                                     claimp, flagp);
    fused_kernel<<<dim3(2048), dim3(256), 0, stream>>>(logits, offs, tids, n_thing,
                                                       keys, blkcnt, maxpb,
                                                       centers, claimp, flagp, out);
}